// Round 6
// baseline (232.444 us; speedup 1.0000x reference)
//
#include <hip/hip_runtime.h>

// RoIAlign: features (2,256,200,304) fp32 NCHW, rois (512,5) fp32,
// out (512,256,7,7) fp32. OUT=7x7, sampling ratio G=2, scale 0.25.
//
// Round 6: transpose widened to 4 channels/lane with uint2 (dwordx2)
// stores: per lane 64 elements = 16 float4 loads + 16 dwordx2 stores
// (0.5 mem-inst/elem vs 0.75 in round 5); each store wave-inst is 512 B
// contiguous. Block = 2 waves = 2 h-rows. Gather unchanged from round 5
// (XCD-swizzled (roi,ph) grid, bf16x2 loads) to keep the delta attributable.

#define OUT_H 7
#define OUT_W 7
constexpr float SPATIAL_SCALE = 0.25f;
constexpr int CN = 256;   // channels
constexpr int FH = 200;
constexpr int FW = 304;
constexpr int N_IMG = 2;
constexpr int N_ROIS = 512;
constexpr size_t PLANE = (size_t)FH * FW;
constexpr size_t NHWC_ELEMS = (size_t)N_IMG * PLANE * CN;
constexpr size_t NHWC_BF16_BYTES = NHWC_ELEMS * sizeof(unsigned short);

__device__ __forceinline__ unsigned short f2bf_rne(float f) {
    unsigned int u = __float_as_uint(f);
    unsigned int r = (u + 0x7FFFu + ((u >> 16) & 1u)) >> 16;  // RNE
    return (unsigned short)r;
}

// ---------------- transpose NCHW fp32 -> NHWC bf16 ----------------
// grid (N_IMG*FH/2, FW/16); 128 threads = 2 waves, one h-row per wave.
// Lane l handles channels 4l..4l+3 (64 lanes cover all 256). Per lane:
// 4 channel-rows x 16 floats = 16 dense float4 loads (whole 64B lines,
// row pitch 1216 B = 19*64), then 16 uint2 stores; wave store = 512 B
// contiguous (64 lanes x 8 B).
__global__ __launch_bounds__(128) void nchw_to_nhwc_bf16(
    const float* __restrict__ in, unsigned short* __restrict__ ws)
{
    const int wave = threadIdx.x >> 6;
    const int lane = threadIdx.x & 63;
    const int nh = blockIdx.x * 2 + wave;  // n*FH + h
    const int n = nh / FH;
    const int h = nh % FH;
    const int c0 = lane * 4;
    const int w0 = blockIdx.y * 16;

    const float* src = in + (((size_t)n * CN + c0) * FH + h) * FW + w0;
    uint2* dst = (uint2*)(ws + (((size_t)n * FH + h) * FW + w0) * CN + c0);

    float4 r[4][4];
#pragma unroll
    for (int ch = 0; ch < 4; ++ch) {
        const float* s = src + (size_t)ch * PLANE;
        r[ch][0] = *(const float4*)(s + 0);
        r[ch][1] = *(const float4*)(s + 4);
        r[ch][2] = *(const float4*)(s + 8);
        r[ch][3] = *(const float4*)(s + 12);
    }

#pragma unroll
    for (int q = 0; q < 4; ++q) {
        const float c0v[4] = {r[0][q].x, r[0][q].y, r[0][q].z, r[0][q].w};
        const float c1v[4] = {r[1][q].x, r[1][q].y, r[1][q].z, r[1][q].w};
        const float c2v[4] = {r[2][q].x, r[2][q].y, r[2][q].z, r[2][q].w};
        const float c3v[4] = {r[3][q].x, r[3][q].y, r[3][q].z, r[3][q].w};
#pragma unroll
        for (int i = 0; i < 4; ++i) {
            uint2 p;
            p.x = (unsigned int)f2bf_rne(c0v[i]) |
                  ((unsigned int)f2bf_rne(c1v[i]) << 16);
            p.y = (unsigned int)f2bf_rne(c2v[i]) |
                  ((unsigned int)f2bf_rne(c3v[i]) << 16);
            dst[(size_t)(q * 4 + i) * (CN / 4)] = p;
        }
    }
}

// ---------------- gather on NHWC bf16: (roi, ph) blocks, XCD-swizzled ----
// 1-D grid of 3584; decode so all 7 ph of a roi share (id % 8) => same XCD.
__global__ __launch_bounds__(128) void roi_align_nhwc_bf16(
    const unsigned short* __restrict__ ws,
    const float* __restrict__ rois,
    float* __restrict__ out)
{
    const int b = blockIdx.x;
    const int x = b & 7;                 // XCD residue
    const int s_id = b >> 3;             // 0..447
    const int r  = (s_id / 7) * 8 + x;   // roi
    const int ph = s_id % 7;             // output row
    const int t  = threadIdx.x;          // channel pair: 2t, 2t+1

    __shared__ float s_roi[5];
    __shared__ int   s_off[28][4];
    __shared__ float s_w[28][4];
    __shared__ int   s_b;

    if (t < 5) s_roi[t] = rois[r * 5 + t];
    __syncthreads();

    if (t < 28) {
        const int s  = t;
        const int gy = s / 14;
        const int ix = s % 14;
        const float x1 = s_roi[1] * SPATIAL_SCALE - 0.5f;
        const float y1 = s_roi[2] * SPATIAL_SCALE - 0.5f;
        const float x2 = s_roi[3] * SPATIAL_SCALE - 0.5f;
        const float y2 = s_roi[4] * SPATIAL_SCALE - 0.5f;
        const float bin_w = (x2 - x1) / OUT_W;
        const float bin_h = (y2 - y1) / OUT_H;
        const float y = y1 + ph * bin_h + (gy + 0.5f) * bin_h * 0.5f;
        const float xf = x1 + (ix >> 1) * bin_w + ((ix & 1) + 0.5f) * bin_w * 0.5f;
        const float validf =
            (y > -1.0f && y < (float)FH && xf > -1.0f && xf < (float)FW) ? 1.0f : 0.0f;
        const float yc = fminf(fmaxf(y, 0.0f), (float)(FH - 1));
        const float xc = fminf(fmaxf(xf, 0.0f), (float)(FW - 1));
        const int y0 = (int)floorf(yc);
        const int x0 = (int)floorf(xc);
        const int y1i = min(y0 + 1, FH - 1);
        const int x1i = min(x0 + 1, FW - 1);
        const float ly = yc - (float)y0;
        const float lx = xc - (float)x0;
        const float hy = 1.0f - ly;
        const float hx = 1.0f - lx;
        s_off[s][0] = (y0  * FW + x0 ) * CN;
        s_off[s][1] = (y0  * FW + x1i) * CN;
        s_off[s][2] = (y1i * FW + x0 ) * CN;
        s_off[s][3] = (y1i * FW + x1i) * CN;
        s_w[s][0] = hy * hx * validf;
        s_w[s][1] = hy * lx * validf;
        s_w[s][2] = ly * hx * validf;
        s_w[s][3] = ly * lx * validf;
    }
    if (t == 0) s_b = (int)s_roi[0];
    __syncthreads();

    const unsigned short* base = ws + (size_t)s_b * (PLANE * CN) + 2 * t;

    float acc0[OUT_W] = {0.f, 0.f, 0.f, 0.f, 0.f, 0.f, 0.f};
    float acc1[OUT_W] = {0.f, 0.f, 0.f, 0.f, 0.f, 0.f, 0.f};
#pragma unroll
    for (int s = 0; s < 28; ++s) {
        const int pw = (s % 14) >> 1;
#pragma unroll
        for (int k = 0; k < 4; ++k) {
            const unsigned int u = *(const unsigned int*)(base + s_off[s][k]);
            const float f0 = __uint_as_float(u << 16);
            const float f1 = __uint_as_float(u & 0xFFFF0000u);
            const float w = s_w[s][k];
            acc0[pw] = fmaf(w, f0, acc0[pw]);
            acc1[pw] = fmaf(w, f1, acc1[pw]);
        }
    }

    const size_t outbase = ((size_t)r * CN + 2 * t) * (OUT_H * OUT_W) + (size_t)ph * OUT_W;
#pragma unroll
    for (int pw = 0; pw < OUT_W; ++pw) {
        out[outbase + pw] = acc0[pw] * 0.25f;
        out[outbase + (OUT_H * OUT_W) + pw] = acc1[pw] * 0.25f;
    }
}

// ---------------- fallback: NCHW gather (round-1 kernel) ----------------
__global__ __launch_bounds__(256) void roi_align_nchw(
    const float* __restrict__ feat,
    const float* __restrict__ rois,
    float* __restrict__ out)
{
    const int r  = blockIdx.x;
    const int ph = blockIdx.y;
    const int c  = threadIdx.x;

    __shared__ float s_roi[5];
    __shared__ int   s_off[28][4];
    __shared__ float s_w[28][4];
    __shared__ int   s_b;

    if (threadIdx.x < 5) s_roi[threadIdx.x] = rois[r * 5 + threadIdx.x];
    __syncthreads();

    if (threadIdx.x < 28) {
        const int s  = threadIdx.x;
        const int gy = s / 14;
        const int ix = s % 14;
        const float x1 = s_roi[1] * SPATIAL_SCALE - 0.5f;
        const float y1 = s_roi[2] * SPATIAL_SCALE - 0.5f;
        const float x2 = s_roi[3] * SPATIAL_SCALE - 0.5f;
        const float y2 = s_roi[4] * SPATIAL_SCALE - 0.5f;
        const float bin_w = (x2 - x1) / OUT_W;
        const float bin_h = (y2 - y1) / OUT_H;
        const float y = y1 + ph * bin_h + (gy + 0.5f) * bin_h * 0.5f;
        const float xf = x1 + (ix >> 1) * bin_w + ((ix & 1) + 0.5f) * bin_w * 0.5f;
        const float validf =
            (y > -1.0f && y < (float)FH && xf > -1.0f && xf < (float)FW) ? 1.0f : 0.0f;
        const float yc = fminf(fmaxf(y, 0.0f), (float)(FH - 1));
        const float xc = fminf(fmaxf(xf, 0.0f), (float)(FW - 1));
        const int y0 = (int)floorf(yc);
        const int x0 = (int)floorf(xc);
        const int y1i = min(y0 + 1, FH - 1);
        const int x1i = min(x0 + 1, FW - 1);
        const float ly = yc - (float)y0;
        const float lx = xc - (float)x0;
        const float hy = 1.0f - ly;
        const float hx = 1.0f - lx;
        s_off[s][0] = y0  * FW + x0;
        s_off[s][1] = y0  * FW + x1i;
        s_off[s][2] = y1i * FW + x0;
        s_off[s][3] = y1i * FW + x1i;
        s_w[s][0] = hy * hx * validf;
        s_w[s][1] = hy * lx * validf;
        s_w[s][2] = ly * hx * validf;
        s_w[s][3] = ly * lx * validf;
    }
    if (threadIdx.x == 0) s_b = (int)s_roi[0];
    __syncthreads();

    const float* base = feat + ((size_t)s_b * CN + c) * PLANE;

    float acc[OUT_W] = {0.f, 0.f, 0.f, 0.f, 0.f, 0.f, 0.f};
#pragma unroll
    for (int s = 0; s < 28; ++s) {
        const float v0 = base[s_off[s][0]];
        const float v1 = base[s_off[s][1]];
        const float v2 = base[s_off[s][2]];
        const float v3 = base[s_off[s][3]];
        acc[(s % 14) >> 1] += s_w[s][0] * v0 + s_w[s][1] * v1 +
                              s_w[s][2] * v2 + s_w[s][3] * v3;
    }

    const size_t outbase = ((size_t)r * CN + c) * (OUT_H * OUT_W) + (size_t)ph * OUT_W;
#pragma unroll
    for (int pw = 0; pw < OUT_W; ++pw) {
        out[outbase + pw] = acc[pw] * 0.25f;
    }
}

extern "C" void kernel_launch(void* const* d_in, const int* in_sizes, int n_in,
                              void* d_out, int out_size, void* d_ws, size_t ws_size,
                              hipStream_t stream) {
    const float* feat = (const float*)d_in[0];
    const float* rois = (const float*)d_in[1];
    float* out = (float*)d_out;

    if (ws_size >= NHWC_BF16_BYTES) {
        unsigned short* ws = (unsigned short*)d_ws;
        dim3 tgrid(N_IMG * FH / 2, FW / 16, 1);      // 200 x 19 = 3800 blocks
        nchw_to_nhwc_bf16<<<tgrid, dim3(128, 1, 1), 0, stream>>>(feat, ws);
        roi_align_nhwc_bf16<<<dim3(N_ROIS * OUT_H, 1, 1), dim3(128, 1, 1), 0, stream>>>(
            ws, rois, out);
    } else {
        dim3 grid(N_ROIS, OUT_H, 1);
        roi_align_nchw<<<grid, dim3(256, 1, 1), 0, stream>>>(feat, rois, out);
    }
}

// Round 7
// 216.582 us; speedup vs baseline: 1.0732x; 1.0732x over previous
//
#include <hip/hip_runtime.h>

// RoIAlign: features (2,256,200,304) fp32 NCHW, rois (512,5) fp32,
// out (512,256,7,7) fp32. OUT=7x7, sampling ratio G=2, scale 0.25.
//
// Round 7: transpose rebuilt as LDS-tiled 64x64 (the NCHW->NHWC relayout is
// a flat 256x60800 matrix transpose). Rounds 2-6 read NCHW with 64 isolated
// 64B requests per wave-instruction -> measured ~2.1 TB/s scattered-line
// ceiling. Tiled: reads are 4x256B sequential streams per instruction,
// writes are full-line 128B/pixel chunks. tile[64][65] fp32: both LDS
// phases are exactly 2 lanes/bank (free on CDNA4). Gather = round-5 best
// (XCD-swizzled (roi,ph) grid, bf16x2 loads), unchanged for attribution.

#define OUT_H 7
#define OUT_W 7
constexpr float SPATIAL_SCALE = 0.25f;
constexpr int CN = 256;   // channels
constexpr int FH = 200;
constexpr int FW = 304;
constexpr int N_IMG = 2;
constexpr int N_ROIS = 512;
constexpr int PIX = FH * FW;               // 60800 = 950 * 64
constexpr size_t PLANE = (size_t)PIX;
constexpr size_t NHWC_ELEMS = (size_t)N_IMG * PLANE * CN;
constexpr size_t NHWC_BF16_BYTES = NHWC_ELEMS * sizeof(unsigned short);

constexpr int CT = 64;   // channel tile
constexpr int PT = 64;   // pixel tile

__device__ __forceinline__ unsigned short f2bf_rne(float f) {
    unsigned int u = __float_as_uint(f);
    unsigned int r = (u + 0x7FFFu + ((u >> 16) & 1u)) >> 16;  // RNE
    return (unsigned short)r;
}

// ---------------- tiled transpose NCHW fp32 -> NHWC bf16 ----------------
// grid (PIX/PT = 950, N_IMG*CN/CT = 8), 256 threads.
// Phase 1: thread (q = t&15, r = t>>4) loads float4 of row (channel)
//   c = r + 16i at pixel offset 4q -> per wave 4 channels x 256 B contiguous.
//   Scatter to tile[c][4q+j]: banks (65c + 4q+j)%32 = (c+4q+j)%32; per instr
//   (fixed i,j) 4k+c covers 0..63 once -> 2 lanes/bank -> free.
// Phase 2: thread (cq = t&15, p0 = t>>4) reads tile[4cq+i][p], packs 4
//   channels -> uint2, stores at pixel p = p0+16i2: per 16-lane cluster one
//   pixel's 64 channels = 128 B contiguous (2 full lines).
__global__ __launch_bounds__(256) void nchw_to_nhwc_bf16_tiled(
    const float* __restrict__ in, unsigned short* __restrict__ ws)
{
    const int pbase = blockIdx.x * PT;
    const int nc = blockIdx.y;           // 0..7
    const int n = nc >> 2;
    const int cbase = (nc & 3) * CT;

    __shared__ float tile[CT][PT + 1];

    {
        const int q = threadIdx.x & 15;  // float4 slot within pixel row
        const int r = threadIdx.x >> 4;  // 0..15
        const float* src = in + ((size_t)n * CN + cbase) * PLANE + pbase + 4 * q;
#pragma unroll
        for (int i = 0; i < 4; ++i) {
            const int c = r + 16 * i;
            const float4 v = *(const float4*)(src + (size_t)c * PLANE);
            tile[c][4 * q + 0] = v.x;
            tile[c][4 * q + 1] = v.y;
            tile[c][4 * q + 2] = v.z;
            tile[c][4 * q + 3] = v.w;
        }
    }
    __syncthreads();
    {
        const int cq = threadIdx.x & 15; // channel quad: channels 4cq..4cq+3
        const int p0 = threadIdx.x >> 4; // 0..15
        unsigned short* dstbase =
            ws + ((size_t)n * PLANE + pbase) * CN + cbase + 4 * cq;
#pragma unroll
        for (int i = 0; i < 4; ++i) {
            const int p = p0 + 16 * i;
            const float f0 = tile[4 * cq + 0][p];
            const float f1 = tile[4 * cq + 1][p];
            const float f2 = tile[4 * cq + 2][p];
            const float f3 = tile[4 * cq + 3][p];
            uint2 pk;
            pk.x = (unsigned int)f2bf_rne(f0) | ((unsigned int)f2bf_rne(f1) << 16);
            pk.y = (unsigned int)f2bf_rne(f2) | ((unsigned int)f2bf_rne(f3) << 16);
            *(uint2*)(dstbase + (size_t)p * CN) = pk;
        }
    }
}

// ---------------- gather on NHWC bf16: (roi, ph) blocks, XCD-swizzled ----
// 1-D grid of 3584; decode so all 7 ph of a roi share (id % 8) => same XCD.
__global__ __launch_bounds__(128) void roi_align_nhwc_bf16(
    const unsigned short* __restrict__ ws,
    const float* __restrict__ rois,
    float* __restrict__ out)
{
    const int b = blockIdx.x;
    const int x = b & 7;                 // XCD residue
    const int s_id = b >> 3;             // 0..447
    const int r  = (s_id / 7) * 8 + x;   // roi
    const int ph = s_id % 7;             // output row
    const int t  = threadIdx.x;          // channel pair: 2t, 2t+1

    __shared__ float s_roi[5];
    __shared__ int   s_off[28][4];
    __shared__ float s_w[28][4];
    __shared__ int   s_b;

    if (t < 5) s_roi[t] = rois[r * 5 + t];
    __syncthreads();

    if (t < 28) {
        const int s  = t;
        const int gy = s / 14;
        const int ix = s % 14;
        const float x1 = s_roi[1] * SPATIAL_SCALE - 0.5f;
        const float y1 = s_roi[2] * SPATIAL_SCALE - 0.5f;
        const float x2 = s_roi[3] * SPATIAL_SCALE - 0.5f;
        const float y2 = s_roi[4] * SPATIAL_SCALE - 0.5f;
        const float bin_w = (x2 - x1) / OUT_W;
        const float bin_h = (y2 - y1) / OUT_H;
        const float y = y1 + ph * bin_h + (gy + 0.5f) * bin_h * 0.5f;
        const float xf = x1 + (ix >> 1) * bin_w + ((ix & 1) + 0.5f) * bin_w * 0.5f;
        const float validf =
            (y > -1.0f && y < (float)FH && xf > -1.0f && xf < (float)FW) ? 1.0f : 0.0f;
        const float yc = fminf(fmaxf(y, 0.0f), (float)(FH - 1));
        const float xc = fminf(fmaxf(xf, 0.0f), (float)(FW - 1));
        const int y0 = (int)floorf(yc);
        const int x0 = (int)floorf(xc);
        const int y1i = min(y0 + 1, FH - 1);
        const int x1i = min(x0 + 1, FW - 1);
        const float ly = yc - (float)y0;
        const float lx = xc - (float)x0;
        const float hy = 1.0f - ly;
        const float hx = 1.0f - lx;
        s_off[s][0] = (y0  * FW + x0 ) * CN;
        s_off[s][1] = (y0  * FW + x1i) * CN;
        s_off[s][2] = (y1i * FW + x0 ) * CN;
        s_off[s][3] = (y1i * FW + x1i) * CN;
        s_w[s][0] = hy * hx * validf;
        s_w[s][1] = hy * lx * validf;
        s_w[s][2] = ly * hx * validf;
        s_w[s][3] = ly * lx * validf;
    }
    if (t == 0) s_b = (int)s_roi[0];
    __syncthreads();

    const unsigned short* base = ws + (size_t)s_b * (PLANE * CN) + 2 * t;

    float acc0[OUT_W] = {0.f, 0.f, 0.f, 0.f, 0.f, 0.f, 0.f};
    float acc1[OUT_W] = {0.f, 0.f, 0.f, 0.f, 0.f, 0.f, 0.f};
#pragma unroll
    for (int s = 0; s < 28; ++s) {
        const int pw = (s % 14) >> 1;
#pragma unroll
        for (int k = 0; k < 4; ++k) {
            const unsigned int u = *(const unsigned int*)(base + s_off[s][k]);
            const float f0 = __uint_as_float(u << 16);
            const float f1 = __uint_as_float(u & 0xFFFF0000u);
            const float w = s_w[s][k];
            acc0[pw] = fmaf(w, f0, acc0[pw]);
            acc1[pw] = fmaf(w, f1, acc1[pw]);
        }
    }

    const size_t outbase = ((size_t)r * CN + 2 * t) * (OUT_H * OUT_W) + (size_t)ph * OUT_W;
#pragma unroll
    for (int pw = 0; pw < OUT_W; ++pw) {
        out[outbase + pw] = acc0[pw] * 0.25f;
        out[outbase + (OUT_H * OUT_W) + pw] = acc1[pw] * 0.25f;
    }
}

// ---------------- fallback: NCHW gather (round-1 kernel) ----------------
__global__ __launch_bounds__(256) void roi_align_nchw(
    const float* __restrict__ feat,
    const float* __restrict__ rois,
    float* __restrict__ out)
{
    const int r  = blockIdx.x;
    const int ph = blockIdx.y;
    const int c  = threadIdx.x;

    __shared__ float s_roi[5];
    __shared__ int   s_off[28][4];
    __shared__ float s_w[28][4];
    __shared__ int   s_b;

    if (threadIdx.x < 5) s_roi[threadIdx.x] = rois[r * 5 + threadIdx.x];
    __syncthreads();

    if (threadIdx.x < 28) {
        const int s  = threadIdx.x;
        const int gy = s / 14;
        const int ix = s % 14;
        const float x1 = s_roi[1] * SPATIAL_SCALE - 0.5f;
        const float y1 = s_roi[2] * SPATIAL_SCALE - 0.5f;
        const float x2 = s_roi[3] * SPATIAL_SCALE - 0.5f;
        const float y2 = s_roi[4] * SPATIAL_SCALE - 0.5f;
        const float bin_w = (x2 - x1) / OUT_W;
        const float bin_h = (y2 - y1) / OUT_H;
        const float y = y1 + ph * bin_h + (gy + 0.5f) * bin_h * 0.5f;
        const float xf = x1 + (ix >> 1) * bin_w + ((ix & 1) + 0.5f) * bin_w * 0.5f;
        const float validf =
            (y > -1.0f && y < (float)FH && xf > -1.0f && xf < (float)FW) ? 1.0f : 0.0f;
        const float yc = fminf(fmaxf(y, 0.0f), (float)(FH - 1));
        const float xc = fminf(fmaxf(xf, 0.0f), (float)(FW - 1));
        const int y0 = (int)floorf(yc);
        const int x0 = (int)floorf(xc);
        const int y1i = min(y0 + 1, FH - 1);
        const int x1i = min(x0 + 1, FW - 1);
        const float ly = yc - (float)y0;
        const float lx = xc - (float)x0;
        const float hy = 1.0f - ly;
        const float hx = 1.0f - lx;
        s_off[s][0] = y0  * FW + x0;
        s_off[s][1] = y0  * FW + x1i;
        s_off[s][2] = y1i * FW + x0;
        s_off[s][3] = y1i * FW + x1i;
        s_w[s][0] = hy * hx * validf;
        s_w[s][1] = hy * lx * validf;
        s_w[s][2] = ly * hx * validf;
        s_w[s][3] = ly * lx * validf;
    }
    if (threadIdx.x == 0) s_b = (int)s_roi[0];
    __syncthreads();

    const float* base = feat + ((size_t)s_b * CN + c) * PLANE;

    float acc[OUT_W] = {0.f, 0.f, 0.f, 0.f, 0.f, 0.f, 0.f};
#pragma unroll
    for (int s = 0; s < 28; ++s) {
        const float v0 = base[s_off[s][0]];
        const float v1 = base[s_off[s][1]];
        const float v2 = base[s_off[s][2]];
        const float v3 = base[s_off[s][3]];
        acc[(s % 14) >> 1] += s_w[s][0] * v0 + s_w[s][1] * v1 +
                              s_w[s][2] * v2 + s_w[s][3] * v3;
    }

    const size_t outbase = ((size_t)r * CN + c) * (OUT_H * OUT_W) + (size_t)ph * OUT_W;
#pragma unroll
    for (int pw = 0; pw < OUT_W; ++pw) {
        out[outbase + pw] = acc[pw] * 0.25f;
    }
}

extern "C" void kernel_launch(void* const* d_in, const int* in_sizes, int n_in,
                              void* d_out, int out_size, void* d_ws, size_t ws_size,
                              hipStream_t stream) {
    const float* feat = (const float*)d_in[0];
    const float* rois = (const float*)d_in[1];
    float* out = (float*)d_out;

    if (ws_size >= NHWC_BF16_BYTES) {
        unsigned short* ws = (unsigned short*)d_ws;
        dim3 tgrid(PIX / PT, (N_IMG * CN) / CT, 1);  // 950 x 8 = 7600 blocks
        nchw_to_nhwc_bf16_tiled<<<tgrid, dim3(256, 1, 1), 0, stream>>>(feat, ws);
        roi_align_nhwc_bf16<<<dim3(N_ROIS * OUT_H, 1, 1), dim3(128, 1, 1), 0, stream>>>(
            ws, rois, out);
    } else {
        dim3 grid(N_ROIS, OUT_H, 1);
        roi_align_nchw<<<grid, dim3(256, 1, 1), 0, stream>>>(feat, rois, out);
    }
}